// Round 11
// baseline (7340.533 us; speedup 1.0000x reference)
//
#include <hip/hip_runtime.h>
#include <hip/hip_bf16.h>

#define NT 50
#define NB 512
#define SD 256
#define BD 1024
#define HD 1024
#define ED 1024
#define MD 256
#define NBLK 768
#define PGSZ (1024 * 256)
#define K1BIG 0x40000000

typedef __attribute__((ext_vector_type(8))) short bf16x8;
typedef __attribute__((ext_vector_type(4))) float f32x4;

// W: plain cached (L1+L2+L3) -- read-only weights
__device__ __forceinline__ void gload_lds16(const void* g, void* l) {
  __builtin_amdgcn_global_load_lds(
      (const __attribute__((address_space(1))) void*)g,
      (__attribute__((address_space(3))) void*)l, 16, 0, 0);
}
// A: sc0 (aux=1) -- bypass L1, read fresh from XCD-local L2
__device__ __forceinline__ void gload_lds16_sc0(const void* g, void* l) {
  __builtin_amdgcn_global_load_lds(
      (const __attribute__((address_space(1))) void*)g,
      (__attribute__((address_space(3))) void*)l, 16, 0, 1);
}

// ---- XCD-local (sc0) activation access ----
__device__ __forceinline__ void aload16(const void* a, f32x4* r) {
  asm volatile("global_load_dwordx4 %0, %1, off sc0" : "=&v"(*r) : "v"(a) : "memory");
}
__device__ __forceinline__ void aload4(const void* a, float* r) {
  asm volatile("global_load_dword %0, %1, off sc0" : "=&v"(*r) : "v"(a) : "memory");
}
#define VMWAIT(N)                                        \
  asm volatile("s_waitcnt vmcnt(" #N ")" ::: "memory");  \
  __builtin_amdgcn_sched_barrier(0);

__device__ __forceinline__ void astore16(void* g, f32x4 v) {
  asm volatile("global_store_dwordx4 %0, %1, off sc0" :: "v"(g), "v"(v) : "memory");
}
__device__ __forceinline__ void astore4(void* g, float v) {
  asm volatile("global_store_dword %0, %1, off sc0" :: "v"(g), "v"(v) : "memory");
}
__device__ __forceinline__ void astore2(void* g, unsigned v) {
  asm volatile("global_store_short %0, %1, off sc0" :: "v"(g), "v"(v) : "memory");
}
__device__ __forceinline__ void ntstore16(void* g, f32x4 v) {
  asm volatile("global_store_dwordx4 %0, %1, off nt" :: "v"(g), "v"(v) : "memory");
}
__device__ __forceinline__ void ntstore4(void* g, float v) {
  asm volatile("global_store_dword %0, %1, off nt" :: "v"(g), "v"(v) : "memory");
}

__device__ __forceinline__ float sigmoidf_(float x) { return 1.0f / (1.0f + __expf(-x)); }
__device__ __forceinline__ float softplusf_(float x) {
  return (x > 0.0f) ? (x + log1pf(__expf(-x))) : log1pf(__expf(x));
}
__device__ __forceinline__ unsigned short bfb(float x) {
  __hip_bfloat16 h = __float2bfloat16(x);
  return __builtin_bit_cast(unsigned short, h);
}

// ---- per-XCD barrier (relaxed atomics, s_sleep backoff) ----
__device__ __forceinline__ void xbar(unsigned* cnt, int inst, int xcd, int nx) {
  asm volatile("s_waitcnt vmcnt(0) lgkmcnt(0)" ::: "memory");
  __syncthreads();
  if (threadIdx.x == 0) {
    unsigned* c = cnt + 256 + (size_t)(inst * 8 + xcd) * 16;
    __hip_atomic_fetch_add(c, 1u, __ATOMIC_RELAXED, __HIP_MEMORY_SCOPE_AGENT);
    while (__hip_atomic_load(c, __ATOMIC_RELAXED, __HIP_MEMORY_SCOPE_AGENT) < (unsigned)nx)
      __builtin_amdgcn_s_sleep(16);
  }
  __syncthreads();
}

// ---- 64x64 GEMM tile, BK=64, RING-3 LDS, all-gload_lds staging, counted vmcnt ----
// EPI: 0 fp32(+bias); 1 relu->bf16(+bias); 3 relu->bf16(+bias+Cadd).
__device__ __noinline__ void gemm64(
    int EPI, char* lds,
    const __hip_bfloat16* __restrict__ A1, int lda1,
    const __hip_bfloat16* __restrict__ A2, int lda2, int K1,
    const __hip_bfloat16* __restrict__ Wr, int ldw, int nIter,
    const float* __restrict__ bias, const float* __restrict__ Cadd,
    float* __restrict__ Cf, __hip_bfloat16* __restrict__ Cb, int ldc, int m0) {
  const int tid = threadIdx.x;
  const int lane = tid & 63, w = tid >> 6;
  const int wr = w >> 1, wc = w & 1;
  f32x4 acc[2][2] = {};
  const __hip_bfloat16* a1r = A1 + (size_t)(m0 + lane) * lda1;
  const __hip_bfloat16* a2r = A2 ? (A2 + (size_t)(m0 + lane) * lda2) : a1r;
  const __hip_bfloat16* wrow = Wr + (size_t)lane * ldw;

  auto stage = [&](int it) {
    const int k0 = it << 6;
    char* la = lds + (size_t)(it % 3) * 16384;
    char* lb = la + 8192;
    const __hip_bfloat16* as = (k0 < K1) ? (a1r + k0) : (a2r + (k0 - K1));
    gload_lds16_sc0(as + (2 * w) * 8, la + (2 * w) * 1024);
    gload_lds16_sc0(as + (2 * w + 1) * 8, la + (2 * w + 1) * 1024);
    gload_lds16(wrow + k0 + (2 * w) * 8, lb + (2 * w) * 1024);
    gload_lds16(wrow + k0 + (2 * w + 1) * 8, lb + (2 * w + 1) * 1024);
  };

  __syncthreads();  // entry: LDS reuse guard
  stage(0);
  stage(1);
  VMWAIT(4)
  __builtin_amdgcn_s_barrier();
  __builtin_amdgcn_sched_barrier(0);

  const int kq = lane >> 4, r15 = lane & 15;
  for (int i = 0; i < nIter; ++i) {
    if (i + 2 < nIter) stage(i + 2);
    const char* la = lds + (size_t)(i % 3) * 16384;
    const char* lb = la + 8192;
#pragma unroll
    for (int s = 0; s < 2; ++s) {
      bf16x8 af[2], bfr[2];
#pragma unroll
      for (int m = 0; m < 2; ++m)
        af[m] = *(const bf16x8*)(la + (size_t)((s * 4 + kq) * 64 + wr * 32 + m * 16 + r15) * 16);
#pragma unroll
      for (int n = 0; n < 2; ++n)
        bfr[n] = *(const bf16x8*)(lb + (size_t)((s * 4 + kq) * 64 + wc * 32 + n * 16 + r15) * 16);
#pragma unroll
      for (int m = 0; m < 2; ++m)
#pragma unroll
        for (int n = 0; n < 2; ++n)
          acc[m][n] = __builtin_amdgcn_mfma_f32_16x16x32_bf16(af[m], bfr[n], acc[m][n], 0, 0, 0);
    }
    if (i + 1 < nIter) {
      if (i + 2 < nIter) {
        VMWAIT(4)
      } else {
        VMWAIT(0)
      }
      __builtin_amdgcn_s_barrier();
      __builtin_amdgcn_sched_barrier(0);
    }
  }

  const int rg = lane >> 4;
  float ad[2][2][4];
  if (EPI == 3) {
#pragma unroll
    for (int m = 0; m < 2; ++m)
#pragma unroll
      for (int n = 0; n < 2; ++n) {
        const int col = wc * 32 + n * 16 + r15;
#pragma unroll
        for (int i2 = 0; i2 < 4; ++i2) {
          const int row = m0 + wr * 32 + m * 16 + rg * 4 + i2;
          aload4(Cadd + (size_t)row * ldc + col, &ad[m][n][i2]);
        }
      }
    VMWAIT(0)
  }
#pragma unroll
  for (int m = 0; m < 2; ++m) {
#pragma unroll
    for (int n = 0; n < 2; ++n) {
      const int col = wc * 32 + n * 16 + r15;
      const float bv = bias ? bias[col] : 0.0f;
#pragma unroll
      for (int i2 = 0; i2 < 4; ++i2) {
        const int row = m0 + wr * 32 + m * 16 + rg * 4 + i2;
        float v = acc[m][n][i2] + bv;
        if (EPI == 3) v += ad[m][n][i2];
        if (EPI == 0) {
          astore4(Cf + (size_t)row * ldc + col, v);
        } else {
          v = v > 0.0f ? v : 0.0f;
          astore2(Cb + (size_t)row * ldc + col, (unsigned)bfb(v));
        }
      }
    }
  }
}

// ---- head GEMM (K=1024) with fused prior/posterior epilogue; W pre-interleaved ----
__device__ __noinline__ void gemm_head64(
    char* lds, const __hip_bfloat16* __restrict__ A,
    const __hip_bfloat16* __restrict__ Wr, const float* __restrict__ bias,
    const float* __restrict__ noise, float* __restrict__ st_o, float* __restrict__ mn_o,
    float* __restrict__ sd_o, const float* __restrict__ ntn,
    __hip_bfloat16* __restrict__ sprev, int isq, int n0, int m0) {
  const int tid = threadIdx.x;
  const int lane = tid & 63, w = tid >> 6;
  const int wr = w >> 1, wc = w & 1;
  f32x4 acc[2][2] = {};
  const __hip_bfloat16* ar = A + (size_t)(m0 + lane) * BD;
  const __hip_bfloat16* wrow = Wr + (size_t)lane * BD;

  auto stage = [&](int it) {
    const int k0 = it << 6;
    char* la = lds + (size_t)(it % 3) * 16384;
    char* lb = la + 8192;
    gload_lds16_sc0(ar + k0 + (2 * w) * 8, la + (2 * w) * 1024);
    gload_lds16_sc0(ar + k0 + (2 * w + 1) * 8, la + (2 * w + 1) * 1024);
    gload_lds16(wrow + k0 + (2 * w) * 8, lb + (2 * w) * 1024);
    gload_lds16(wrow + k0 + (2 * w + 1) * 8, lb + (2 * w + 1) * 1024);
  };

  __syncthreads();
  stage(0);
  stage(1);
  VMWAIT(4)
  __builtin_amdgcn_s_barrier();
  __builtin_amdgcn_sched_barrier(0);

  const int kq = lane >> 4, r15 = lane & 15;
  for (int i = 0; i < 16; ++i) {
    if (i + 2 < 16) stage(i + 2);
    const char* la = lds + (size_t)(i % 3) * 16384;
    const char* lb = la + 8192;
#pragma unroll
    for (int s = 0; s < 2; ++s) {
      bf16x8 af[2], bfr[2];
#pragma unroll
      for (int m = 0; m < 2; ++m)
        af[m] = *(const bf16x8*)(la + (size_t)((s * 4 + kq) * 64 + wr * 32 + m * 16 + r15) * 16);
#pragma unroll
      for (int n = 0; n < 2; ++n)
        bfr[n] = *(const bf16x8*)(lb + (size_t)((s * 4 + kq) * 64 + wc * 32 + n * 16 + r15) * 16);
#pragma unroll
      for (int m = 0; m < 2; ++m)
#pragma unroll
        for (int n = 0; n < 2; ++n)
          acc[m][n] = __builtin_amdgcn_mfma_f32_16x16x32_bf16(af[m], bfr[n], acc[m][n], 0, 0, 0);
    }
    if (i + 1 < 16) {
      if (i + 2 < 16) {
        VMWAIT(4)
      } else {
        VMWAIT(0)
      }
      __builtin_amdgcn_s_barrier();
      __builtin_amdgcn_sched_barrier(0);
    }
  }

  const int rg = lane >> 4;
  const bool even = (r15 & 1) == 0;
#pragma unroll
  for (int m = 0; m < 2; ++m) {
#pragma unroll
    for (int n = 0; n < 2; ++n) {
      const int col = n0 + wc * 32 + n * 16 + r15;  // interleaved mean/raw
      const int j = col >> 1;
      const float bv = bias[col];
#pragma unroll
      for (int i2 = 0; i2 < 4; ++i2) {
        const int row = m0 + wr * 32 + m * 16 + rg * 4 + i2;
        float v = acc[m][n][i2] + bv;
        float partner = __shfl_xor(v, 1);
        float mean = even ? v : partner;
        float raw = even ? partner : v;
        float sd = fminf(softplusf_(raw) + 0.1f, 5.0f);
        const size_t o = (size_t)row * SD + j;
        if (even) {
          float st = mean + sd * noise[o];
          ntstore4(mn_o + o, mean);
          ntstore4(st_o + o, st);
          if (isq) astore2(sprev + o, (unsigned)bfb(st * ntn[row]));
        } else {
          ntstore4(sd_o + o, sd);
        }
      }
    }
  }
}

struct Args {
  const float *prev_state, *actions, *prev_belief, *observations, *nonterminals,
      *me, *mp, *noise_p, *noise_q,
      *W_sa, *b_sa, *W_ih, *b_ih, *W_hh, *b_hh,
      *W_bp, *b_bp, *W_sp, *b_sp, *W_bq, *b_bq, *W_sq, *b_sq;
  float* out;
  unsigned* cnt;
  __hip_bfloat16 *Wsa, *Wih, *Whh, *Wbp, *Wbq, *Wsp, *Wsq;
  __hip_bfloat16 *actme, *obsmp, *sprev, *bel, *hid, *hpb, *hqb;
  float *gi, *gh, *hq_obs;
  float *bsp_ro, *bsq_ro;
};

// ---------------- prep ----------------
__global__ __launch_bounds__(256) void prep(Args P) {
  const int gtid = blockIdx.x * 256 + threadIdx.x;
  for (int i = gtid; i < BD * 576; i += PGSZ) {  // W_sa padded K 544->576
    int r = i / 576, k = i - r * 576;
    P.Wsa[i] = __float2bfloat16(k < 544 ? P.W_sa[(size_t)r * 544 + k] : 0.0f);
  }
  for (int i = gtid; i < 3 * BD * BD; i += PGSZ) P.Wih[i] = __float2bfloat16(P.W_ih[i]);
  for (int i = gtid; i < 3 * BD * BD; i += PGSZ) P.Whh[i] = __float2bfloat16(P.W_hh[i]);
  for (int i = gtid; i < HD * BD; i += PGSZ) P.Wbp[i] = __float2bfloat16(P.W_bp[i]);
  for (int i = gtid; i < HD * 2304; i += PGSZ) P.Wbq[i] = __float2bfloat16(P.W_bq[i]);
  for (int i = gtid; i < 512 * HD; i += PGSZ) {  // head W interleave
    int r = i >> 10, k = i & 1023;
    int dr = (r < 256) ? (2 * r) : (2 * (r - 256) + 1);
    P.Wsp[(size_t)dr * 1024 + k] = __float2bfloat16(P.W_sp[i]);
    P.Wsq[(size_t)dr * 1024 + k] = __float2bfloat16(P.W_sq[i]);
  }
  for (int i = gtid; i < 512; i += PGSZ) {
    int dr = (i < 256) ? (2 * i) : (2 * (i - 256) + 1);
    P.bsp_ro[dr] = P.b_sp[i];
    P.bsq_ro[dr] = P.b_sq[i];
  }
  for (int i = gtid; i < NT * NB * 320; i += PGSZ) {  // [act(32)|me(256)|pad(32)]
    int tb = i / 320, j = i - tb * 320;
    float v = (j < 32) ? P.actions[(size_t)tb * 32 + j]
                       : (j < 288 ? P.me[(size_t)tb * 256 + (j - 32)] : 0.0f);
    P.actme[i] = __float2bfloat16(v);
  }
  for (int i = gtid; i < NB * 1280; i += PGSZ) {  // obsmp(0)
    int bb = i / 1280, j = i - bb * 1280;
    float v = (j < ED) ? P.observations[(size_t)bb * ED + j] : P.mp[(size_t)bb * MD + (j - ED)];
    P.obsmp[i] = __float2bfloat16(v);
  }
  for (int i = gtid; i < NB * SD; i += PGSZ) {
    int r = i >> 8;
    P.sprev[i] = __float2bfloat16(P.prev_state[i] * P.nonterminals[r]);
  }
  for (int i = gtid; i < NB * BD; i += PGSZ) P.bel[i] = __float2bfloat16(P.prev_belief[i]);
}

// ---------------- mega: XCD m-partition + atomic-ticket job stealing ----------------
__global__ __launch_bounds__(256, 3) void mega(Args P) {
  __shared__ alignas(16) char lds[49152];
  __shared__ int sh[4];
  const int tid = threadIdx.x;

  if (tid == 0) {
    unsigned x;
    asm volatile("s_getreg_b32 %0, hwreg(HW_REG_XCC_ID)" : "=s"(x));
    x &= 7u;
    unsigned s = __hip_atomic_fetch_add(P.cnt + x * 16, 1u, __ATOMIC_RELAXED,
                                        __HIP_MEMORY_SCOPE_AGENT);
    sh[0] = (int)x;
    sh[1] = (int)s;
  }
  __syncthreads();
  const int xcd = sh[0], slot = sh[1];

  if (tid == 0) {
    __hip_atomic_fetch_add(P.cnt + 128, 1u, __ATOMIC_RELAXED, __HIP_MEMORY_SCOPE_AGENT);
    while (__hip_atomic_load(P.cnt + 128, __ATOMIC_RELAXED, __HIP_MEMORY_SCOPE_AGENT) <
           (unsigned)NBLK)
      __builtin_amdgcn_s_sleep(16);
    sh[2] = (int)__hip_atomic_load(P.cnt + xcd * 16, __ATOMIC_RELAXED,
                                   __HIP_MEMORY_SCOPE_AGENT);
  }
  __syncthreads();
  const int nx = sh[2];
  const int m0 = xcd * 64;
  const size_t o_ps = (size_t)NT * NB * BD;
  const size_t blk = (size_t)NT * NB * SD;

#define NEXTJOB(tk, J, out_j)                                                              \
  {                                                                                        \
    __syncthreads();                                                                       \
    if (tid == 0)                                                                          \
      sh[3] = (int)__hip_atomic_fetch_add((tk), 1u, __ATOMIC_RELAXED,                      \
                                          __HIP_MEMORY_SCOPE_AGENT);                       \
    __syncthreads();                                                                       \
    out_j = (sh[3] < (J)) ? sh[3] : -1;                                                    \
  }

  for (int t = 0; t < NT; ++t) {
    const int inst = t * 5;
    unsigned* tkbase = P.cnt + 32768;
    // ---- A: hid (16 jobs, 9 it) || gh (48 jobs, 16 it) ----
    {
      unsigned* tk = tkbase + (size_t)((t * 5 + 0) * 8 + xcd) * 16;
      for (;;) {
        int j;
        NEXTJOB(tk, 64, j)
        if (j < 0) break;
        if (j < 16) {
          gemm64(1, lds, P.sprev, SD, P.actme + (size_t)t * NB * 320, 320, 256,
                 P.Wsa + (size_t)j * 64 * 576, 576, 9,
                 P.b_sa + j * 64, nullptr, nullptr, P.hid + j * 64, BD, m0);
        } else {
          const int n = j - 16;
          gemm64(0, lds, P.bel, BD, nullptr, 0, K1BIG,
                 P.Whh + (size_t)n * 64 * BD, BD, 16,
                 P.b_hh + n * 64, nullptr, P.gh + n * 64, nullptr, 3 * BD, m0);
        }
      }
    }
    xbar(P.cnt, inst + 0, xcd, nx);
    // ---- B: gi (48 jobs, 16 it) || hq_obs (16 jobs, 20 it) ----
    {
      unsigned* tk = tkbase + (size_t)((t * 5 + 1) * 8 + xcd) * 16;
      for (;;) {
        int j;
        NEXTJOB(tk, 64, j)
        if (j < 0) break;
        if (j < 48) {
          gemm64(0, lds, P.hid, BD, nullptr, 0, K1BIG,
                 P.Wih + (size_t)j * 64 * BD, BD, 16,
                 P.b_ih + j * 64, nullptr, P.gi + j * 64, nullptr, 3 * BD, m0);
        } else {
          const int n = j - 48;
          gemm64(0, lds, P.obsmp, 1280, nullptr, 0, K1BIG,
                 P.Wbq + (size_t)n * 64 * 2304 + 1024, 2304, 20,
                 nullptr, nullptr, P.hq_obs + n * 64, nullptr, 1024, m0);
        }
      }
    }
    xbar(P.cnt, inst + 1, xcd, nx);
    // ---- C: GRU pointwise (fp32 gi/gh) + obsmp(t+1) pack ----
    for (int u = slot * 256 + tid; u < 8192; u += nx * 256) {
      const int r = m0 + (u >> 7), j0 = (u & 127) << 3;
      const float* gib = P.gi + (size_t)r * 3072 + j0;
      const float* ghb = P.gh + (size_t)r * 3072 + j0;
      f32x4 ir0, ir1, iz0, iz1, in0, in1, hr0, hr1, hz0, hz1, hn0, hn1, hbv;
      aload16(gib, &ir0);
      aload16(gib + 4, &ir1);
      aload16(gib + 1024, &iz0);
      aload16(gib + 1028, &iz1);
      aload16(gib + 2048, &in0);
      aload16(gib + 2052, &in1);
      aload16(ghb, &hr0);
      aload16(ghb + 4, &hr1);
      aload16(ghb + 1024, &hz0);
      aload16(ghb + 1028, &hz1);
      aload16(ghb + 2048, &hn0);
      aload16(ghb + 2052, &hn1);
      aload16(P.bel + (size_t)r * BD + j0, &hbv);
      VMWAIT(0)
      bf16x8 hb = __builtin_bit_cast(bf16x8, hbv);
      float o[8];
      unsigned short nb[8];
#pragma unroll
      for (int k = 0; k < 8; ++k) {
        float gr = (k < 4 ? ir0[k] : ir1[k - 4]) + (k < 4 ? hr0[k] : hr1[k - 4]);
        float gz = (k < 4 ? iz0[k] : iz1[k - 4]) + (k < 4 ? hz0[k] : hz1[k - 4]);
        float hn = (k < 4 ? hn0[k] : hn1[k - 4]);
        float in_ = (k < 4 ? in0[k] : in1[k - 4]);
        float r_ = sigmoidf_(gr);
        float z_ = sigmoidf_(gz);
        float n_ = tanhf(in_ + r_ * hn);
        __hip_bfloat16 hv16 = __builtin_bit_cast(__hip_bfloat16, (unsigned short)hb[k]);
        float hv = __bfloat162float(hv16);
        float bel = (1.0f - z_) * n_ + z_ * hv;
        o[k] = bel;
        nb[k] = bfb(bel);
      }
      float* ob = P.out + (size_t)t * NB * BD + (size_t)r * BD + j0;
      ntstore16(ob, f32x4{o[0], o[1], o[2], o[3]});
      ntstore16(ob + 4, f32x4{o[4], o[5], o[6], o[7]});
      astore16(P.bel + (size_t)r * BD + j0, __builtin_bit_cast(f32x4, *(bf16x8*)nb));
    }
    if (t + 1 < NT) {
      for (int v = slot * 256 + tid; v < 5120; v += nx * 256) {
        const int r = m0 + v / 80, c0 = (v % 80) << 4;
        const float* src = (c0 < ED)
            ? (P.observations + (size_t)(t + 1) * NB * ED + (size_t)r * ED + c0)
            : (P.mp + (size_t)(t + 1) * NB * MD + (size_t)r * MD + (c0 - ED));
        unsigned short nb[16];
#pragma unroll
        for (int q = 0; q < 4; ++q) {
          f32x4 vv = *(const f32x4*)(src + q * 4);
#pragma unroll
          for (int kk = 0; kk < 4; ++kk) nb[q * 4 + kk] = bfb(vv[kk]);
        }
        astore16(P.obsmp + (size_t)r * 1280 + c0, __builtin_bit_cast(f32x4, *(bf16x8*)nb));
        astore16(P.obsmp + (size_t)r * 1280 + c0 + 8,
                 __builtin_bit_cast(f32x4, *(bf16x8*)(nb + 8)));
      }
    }
    xbar(P.cnt, inst + 2, xcd, nx);
    // ---- D: hp (16 jobs) || hq = bel@Wbq[:1024] + hq_obs (16 jobs) ----
    {
      unsigned* tk = tkbase + (size_t)((t * 5 + 3) * 8 + xcd) * 16;
      for (;;) {
        int j;
        NEXTJOB(tk, 32, j)
        if (j < 0) break;
        if (j < 16) {
          gemm64(1, lds, P.bel, BD, nullptr, 0, K1BIG,
                 P.Wbp + (size_t)j * 64 * BD, BD, 16,
                 P.b_bp + j * 64, nullptr, nullptr, P.hpb + j * 64, HD, m0);
        } else {
          const int n = j - 16;
          gemm64(3, lds, P.bel, BD, nullptr, 0, K1BIG,
                 P.Wbq + (size_t)n * 64 * 2304, 2304, 16,
                 P.b_bq + n * 64, P.hq_obs + n * 64, nullptr, P.hqb + n * 64, HD, m0);
        }
      }
    }
    xbar(P.cnt, inst + 3, xcd, nx);
    // ---- E: p/q heads with fused epilogue + sprev carry (16 jobs) ----
    {
      const float* ntn = P.nonterminals + (size_t)((t + 1 < NT) ? t + 1 : t) * NB;
      const size_t to = (size_t)t * NB * SD;
      unsigned* tk = tkbase + (size_t)((t * 5 + 4) * 8 + xcd) * 16;
      for (;;) {
        int j;
        NEXTJOB(tk, 16, j)
        if (j < 0) break;
        if (j < 8)
          gemm_head64(lds, P.hpb, P.Wsp + (size_t)j * 64 * BD, P.bsp_ro,
                      P.noise_p + to, P.out + o_ps + to, P.out + o_ps + blk + to,
                      P.out + o_ps + 2 * blk + to, ntn, P.sprev, 0, j * 64, m0);
        else
          gemm_head64(lds, P.hqb, P.Wsq + (size_t)(j - 8) * 64 * BD, P.bsq_ro,
                      P.noise_q + to, P.out + o_ps + 3 * blk + to,
                      P.out + o_ps + 4 * blk + to, P.out + o_ps + 5 * blk + to,
                      ntn, P.sprev, 1, (j - 8) * 64, m0);
      }
    }
    xbar(P.cnt, inst + 4, xcd, nx);
  }
}

// ---------------- host ----------------

extern "C" void kernel_launch(void* const* d_in, const int* in_sizes, int n_in,
                              void* d_out, int out_size, void* d_ws, size_t ws_size,
                              hipStream_t stream) {
  Args P;
  P.prev_state = (const float*)d_in[0];
  P.actions = (const float*)d_in[1];
  P.prev_belief = (const float*)d_in[2];
  P.observations = (const float*)d_in[3];
  P.nonterminals = (const float*)d_in[4];
  P.me = (const float*)d_in[5];
  P.mp = (const float*)d_in[6];
  P.noise_p = (const float*)d_in[7];
  P.noise_q = (const float*)d_in[8];
  P.W_sa = (const float*)d_in[9];  P.b_sa = (const float*)d_in[10];
  P.W_ih = (const float*)d_in[11]; P.b_ih = (const float*)d_in[12];
  P.W_hh = (const float*)d_in[13]; P.b_hh = (const float*)d_in[14];
  P.W_bp = (const float*)d_in[15]; P.b_bp = (const float*)d_in[16];
  P.W_sp = (const float*)d_in[17]; P.b_sp = (const float*)d_in[18];
  P.W_bq = (const float*)d_in[19]; P.b_bq = (const float*)d_in[20];
  P.W_sq = (const float*)d_in[21]; P.b_sq = (const float*)d_in[22];
  P.out = (float*)d_out;

  char* p = (char*)d_ws;
  auto carve = [&](size_t bytes) -> char* {
    char* r = p;
    p += (bytes + 255) & ~(size_t)255;
    return r;
  };
  const size_t cnt_bytes = (size_t)65536 * 4;  // slots + barrier lines + tickets
  P.cnt = (unsigned*)carve(cnt_bytes);
  P.Wsa = (__hip_bfloat16*)carve((size_t)BD * 576 * 2);
  P.Wih = (__hip_bfloat16*)carve((size_t)3 * BD * BD * 2);
  P.Whh = (__hip_bfloat16*)carve((size_t)3 * BD * BD * 2);
  P.Wbp = (__hip_bfloat16*)carve((size_t)HD * BD * 2);
  P.Wbq = (__hip_bfloat16*)carve((size_t)HD * 2304 * 2);
  P.Wsp = (__hip_bfloat16*)carve((size_t)512 * HD * 2);
  P.Wsq = (__hip_bfloat16*)carve((size_t)512 * HD * 2);
  P.bsp_ro = (float*)carve(512 * 4);
  P.bsq_ro = (float*)carve(512 * 4);
  P.actme = (__hip_bfloat16*)carve((size_t)NT * NB * 320 * 2);
  P.obsmp = (__hip_bfloat16*)carve((size_t)NB * 1280 * 2);
  P.sprev = (__hip_bfloat16*)carve((size_t)NB * SD * 2);
  P.bel = (__hip_bfloat16*)carve((size_t)NB * BD * 2);
  P.hid = (__hip_bfloat16*)carve((size_t)NB * BD * 2);
  P.hpb = (__hip_bfloat16*)carve((size_t)NB * HD * 2);
  P.hqb = (__hip_bfloat16*)carve((size_t)NB * HD * 2);
  P.gi = (float*)carve((size_t)NB * 3 * BD * 4);
  P.gh = (float*)carve((size_t)NB * 3 * BD * 4);
  P.hq_obs = (float*)carve((size_t)NB * HD * 4);

  hipMemsetAsync(P.cnt, 0, cnt_bytes, stream);
  prep<<<1024, 256, 0, stream>>>(P);
  mega<<<NBLK, 256, 0, stream>>>(P);
}

// Round 12
// 5279.044 us; speedup vs baseline: 1.3905x; 1.3905x over previous
//
#include <hip/hip_runtime.h>
#include <hip/hip_bf16.h>

#define NT 50
#define NB 512
#define SD 256
#define BD 1024
#define HD 1024
#define ED 1024
#define MD 256
#define NBLK 512
#define PGSZ (1024 * 256)
#define K1BIG 0x40000000
#define WPRE_OFF 49152

typedef __attribute__((ext_vector_type(8))) short bf16x8;
typedef __attribute__((ext_vector_type(4))) float f32x4;

// W: plain cached (L1+L2+L3) -- read-only weights
__device__ __forceinline__ void gload_lds16(const void* g, void* l) {
  __builtin_amdgcn_global_load_lds(
      (const __attribute__((address_space(1))) void*)g,
      (__attribute__((address_space(3))) void*)l, 16, 0, 0);
}
// A: sc0 (aux=1) -- bypass L1, read fresh from XCD-local L2
__device__ __forceinline__ void gload_lds16_sc0(const void* g, void* l) {
  __builtin_amdgcn_global_load_lds(
      (const __attribute__((address_space(1))) void*)g,
      (__attribute__((address_space(3))) void*)l, 16, 0, 1);
}

// ---- XCD-local (sc0) activation access ----
__device__ __forceinline__ void aload16(const void* a, f32x4* r) {
  asm volatile("global_load_dwordx4 %0, %1, off sc0" : "=&v"(*r) : "v"(a) : "memory");
}
__device__ __forceinline__ void aload4(const void* a, float* r) {
  asm volatile("global_load_dword %0, %1, off sc0" : "=&v"(*r) : "v"(a) : "memory");
}
#define VMWAIT(N)                                        \
  asm volatile("s_waitcnt vmcnt(" #N ")" ::: "memory");  \
  __builtin_amdgcn_sched_barrier(0);

__device__ __forceinline__ void astore16(void* g, f32x4 v) {
  asm volatile("global_store_dwordx4 %0, %1, off sc0" :: "v"(g), "v"(v) : "memory");
}
__device__ __forceinline__ void astore4(void* g, float v) {
  asm volatile("global_store_dword %0, %1, off sc0" :: "v"(g), "v"(v) : "memory");
}
__device__ __forceinline__ void astore2(void* g, unsigned v) {
  asm volatile("global_store_short %0, %1, off sc0" :: "v"(g), "v"(v) : "memory");
}
__device__ __forceinline__ void ntstore16(void* g, f32x4 v) {
  asm volatile("global_store_dwordx4 %0, %1, off nt" :: "v"(g), "v"(v) : "memory");
}
__device__ __forceinline__ void ntstore4(void* g, float v) {
  asm volatile("global_store_dword %0, %1, off nt" :: "v"(g), "v"(v) : "memory");
}

__device__ __forceinline__ float sigmoidf_(float x) { return 1.0f / (1.0f + __expf(-x)); }
__device__ __forceinline__ float softplusf_(float x) {
  return (x > 0.0f) ? (x + log1pf(__expf(-x))) : log1pf(__expf(x));
}
__device__ __forceinline__ unsigned short bfb(float x) {
  __hip_bfloat16 h = __float2bfloat16(x);
  return __builtin_bit_cast(unsigned short, h);
}

// issue W chunks 0..2 of a job into the wpre region (6 gload_lds, no wait)
__device__ __forceinline__ void wpre_issue(const __hip_bfloat16* W, int ldw,
                                           char* lds, int tid) {
  const int w = tid >> 6, lane = tid & 63;
  const __hip_bfloat16* wrow = W + (size_t)lane * ldw;
  char* wpre = lds + WPRE_OFF;
#pragma unroll
  for (int c = 0; c < 3; ++c) {
    gload_lds16(wrow + (c << 6) + (2 * w) * 8, wpre + c * 8192 + (2 * w) * 1024);
    gload_lds16(wrow + (c << 6) + (2 * w + 1) * 8, wpre + c * 8192 + (2 * w + 1) * 1024);
  }
}

// ---- per-XCD barrier with next-job W-prefetch issued during the wait ----
__device__ __forceinline__ void xbar_pf(unsigned* cnt, int inst, int xcd, int nx,
                                        const __hip_bfloat16* nextW, int nextLdw,
                                        char* lds, int tid) {
  asm volatile("s_waitcnt vmcnt(0) lgkmcnt(0)" ::: "memory");
  __syncthreads();
  unsigned* c = cnt + 256 + (size_t)(inst * 8 + xcd) * 16;
  if (tid == 0)
    __hip_atomic_fetch_add(c, 1u, __ATOMIC_RELAXED, __HIP_MEMORY_SCOPE_AGENT);
  if (nextW) wpre_issue(nextW, nextLdw, lds, tid);  // fetch during the spin
  if (tid == 0) {
    while (__hip_atomic_load(c, __ATOMIC_RELAXED, __HIP_MEMORY_SCOPE_AGENT) < (unsigned)nx)
      __builtin_amdgcn_s_sleep(2);
  }
  __syncthreads();
}

// ---- 64x64 GEMM tile, BK=64, ring-3 LDS + wpre'd first 3 W-chunks ----
// EPI: 0 fp32(+bias); 1 relu->bf16(+bias); 3 relu->bf16(+bias+Cadd).
__device__ __noinline__ void gemm64(
    int EPI, char* lds, bool pre,
    const __hip_bfloat16* __restrict__ A1, int lda1,
    const __hip_bfloat16* __restrict__ A2, int lda2, int K1,
    const __hip_bfloat16* __restrict__ Wr, int ldw, int nIter,
    const float* __restrict__ bias, const float* __restrict__ Cadd,
    float* __restrict__ Cf, __hip_bfloat16* __restrict__ Cb, int ldc, int m0) {
  const int tid = threadIdx.x;
  const int lane = tid & 63, w = tid >> 6;
  const int wr = w >> 1, wc = w & 1;
  f32x4 acc[2][2] = {};
  const __hip_bfloat16* a1r = A1 + (size_t)(m0 + lane) * lda1;
  const __hip_bfloat16* a2r = A2 ? (A2 + (size_t)(m0 + lane) * lda2) : a1r;
  const __hip_bfloat16* wrow = Wr + (size_t)lane * ldw;
  char* wpre = lds + WPRE_OFF;

  auto aissue = [&](int it) {
    const int k0 = it << 6;
    char* la = lds + (size_t)(it % 3) * 16384;
    const __hip_bfloat16* as = (k0 < K1) ? (a1r + k0) : (a2r + (k0 - K1));
    gload_lds16_sc0(as + (2 * w) * 8, la + (2 * w) * 1024);
    gload_lds16_sc0(as + (2 * w + 1) * 8, la + (2 * w + 1) * 1024);
  };
  auto stageAW = [&](int it) {
    const int k0 = it << 6;
    char* la = lds + (size_t)(it % 3) * 16384;
    char* lb = la + 8192;
    const __hip_bfloat16* as = (k0 < K1) ? (a1r + k0) : (a2r + (k0 - K1));
    gload_lds16_sc0(as + (2 * w) * 8, la + (2 * w) * 1024);
    gload_lds16_sc0(as + (2 * w + 1) * 8, la + (2 * w + 1) * 1024);
    gload_lds16(wrow + k0 + (2 * w) * 8, lb + (2 * w) * 1024);
    gload_lds16(wrow + k0 + (2 * w + 1) * 8, lb + (2 * w + 1) * 1024);
  };

  __syncthreads();                       // LDS reuse guard
  if (!pre) wpre_issue(Wr, ldw, lds, tid);  // 2nd job in a phase: self-prefetch
  aissue(0);
  aissue(1);
  aissue(2);
  VMWAIT(4)                              // W-pre (older) + A0 done; A1,A2 pending
  __builtin_amdgcn_s_barrier();
  __builtin_amdgcn_sched_barrier(0);

  const int kq = lane >> 4, r15 = lane & 15;
  for (int i = 0; i < nIter; ++i) {
    const char* la = lds + (size_t)(i % 3) * 16384;
    const char* lb = (i < 3) ? (wpre + (size_t)i * 8192) : (la + 8192);
#pragma unroll
    for (int s = 0; s < 2; ++s) {
      bf16x8 af[2], bfr[2];
#pragma unroll
      for (int m = 0; m < 2; ++m)
        af[m] = *(const bf16x8*)(la + (size_t)((s * 4 + kq) * 64 + wr * 32 + m * 16 + r15) * 16);
#pragma unroll
      for (int n = 0; n < 2; ++n)
        bfr[n] = *(const bf16x8*)(lb + (size_t)((s * 4 + kq) * 64 + wc * 32 + n * 16 + r15) * 16);
#pragma unroll
      for (int m = 0; m < 2; ++m)
#pragma unroll
        for (int n = 0; n < 2; ++n)
          acc[m][n] = __builtin_amdgcn_mfma_f32_16x16x32_bf16(af[m], bfr[n], acc[m][n], 0, 0, 0);
    }
    if (i + 1 < nIter) {
      if (i == 0) {
        VMWAIT(2)        // A1 done; A2 pending
      } else if (i + 2 < nIter) {
        VMWAIT(4)        // stage(i+1) done; stage(i+2) pending
      } else {
        VMWAIT(0)
      }
      __builtin_amdgcn_s_barrier();
      __builtin_amdgcn_sched_barrier(0);
      if (i + 3 < nIter) stageAW(i + 3);
    }
  }

  const int rg = lane >> 4;
  float ad[2][2][4];
  if (EPI == 3) {
#pragma unroll
    for (int m = 0; m < 2; ++m)
#pragma unroll
      for (int n = 0; n < 2; ++n) {
        const int col = wc * 32 + n * 16 + r15;
#pragma unroll
        for (int i2 = 0; i2 < 4; ++i2) {
          const int row = m0 + wr * 32 + m * 16 + rg * 4 + i2;
          aload4(Cadd + (size_t)row * ldc + col, &ad[m][n][i2]);
        }
      }
    VMWAIT(0)
  }
#pragma unroll
  for (int m = 0; m < 2; ++m) {
#pragma unroll
    for (int n = 0; n < 2; ++n) {
      const int col = wc * 32 + n * 16 + r15;
      const float bv = bias ? bias[col] : 0.0f;
#pragma unroll
      for (int i2 = 0; i2 < 4; ++i2) {
        const int row = m0 + wr * 32 + m * 16 + rg * 4 + i2;
        float v = acc[m][n][i2] + bv;
        if (EPI == 3) v += ad[m][n][i2];
        if (EPI == 0) {
          astore4(Cf + (size_t)row * ldc + col, v);
        } else {
          v = v > 0.0f ? v : 0.0f;
          astore2(Cb + (size_t)row * ldc + col, (unsigned)bfb(v));
        }
      }
    }
  }
}

// ---- head GEMM (K=1024) with fused prior/posterior epilogue; W pre-interleaved ----
__device__ __noinline__ void gemm_head64(
    char* lds, bool pre, const __hip_bfloat16* __restrict__ A,
    const __hip_bfloat16* __restrict__ Wr, const float* __restrict__ bias,
    const float* __restrict__ noise, float* __restrict__ st_o, float* __restrict__ mn_o,
    float* __restrict__ sd_o, const float* __restrict__ ntn,
    __hip_bfloat16* __restrict__ sprev, int isq, int n0, int m0) {
  const int tid = threadIdx.x;
  const int lane = tid & 63, w = tid >> 6;
  const int wr = w >> 1, wc = w & 1;
  f32x4 acc[2][2] = {};
  const __hip_bfloat16* ar = A + (size_t)(m0 + lane) * BD;
  const __hip_bfloat16* wrow = Wr + (size_t)lane * BD;
  char* wpre = lds + WPRE_OFF;

  auto aissue = [&](int it) {
    const int k0 = it << 6;
    char* la = lds + (size_t)(it % 3) * 16384;
    gload_lds16_sc0(ar + k0 + (2 * w) * 8, la + (2 * w) * 1024);
    gload_lds16_sc0(ar + k0 + (2 * w + 1) * 8, la + (2 * w + 1) * 1024);
  };
  auto stageAW = [&](int it) {
    const int k0 = it << 6;
    char* la = lds + (size_t)(it % 3) * 16384;
    char* lb = la + 8192;
    gload_lds16_sc0(ar + k0 + (2 * w) * 8, la + (2 * w) * 1024);
    gload_lds16_sc0(ar + k0 + (2 * w + 1) * 8, la + (2 * w + 1) * 1024);
    gload_lds16(wrow + k0 + (2 * w) * 8, lb + (2 * w) * 1024);
    gload_lds16(wrow + k0 + (2 * w + 1) * 8, lb + (2 * w + 1) * 1024);
  };

  __syncthreads();
  if (!pre) wpre_issue(Wr, BD, lds, tid);
  aissue(0);
  aissue(1);
  aissue(2);
  VMWAIT(4)
  __builtin_amdgcn_s_barrier();
  __builtin_amdgcn_sched_barrier(0);

  const int kq = lane >> 4, r15 = lane & 15;
  for (int i = 0; i < 16; ++i) {
    const char* la = lds + (size_t)(i % 3) * 16384;
    const char* lb = (i < 3) ? (wpre + (size_t)i * 8192) : (la + 8192);
#pragma unroll
    for (int s = 0; s < 2; ++s) {
      bf16x8 af[2], bfr[2];
#pragma unroll
      for (int m = 0; m < 2; ++m)
        af[m] = *(const bf16x8*)(la + (size_t)((s * 4 + kq) * 64 + wr * 32 + m * 16 + r15) * 16);
#pragma unroll
      for (int n = 0; n < 2; ++n)
        bfr[n] = *(const bf16x8*)(lb + (size_t)((s * 4 + kq) * 64 + wc * 32 + n * 16 + r15) * 16);
#pragma unroll
      for (int m = 0; m < 2; ++m)
#pragma unroll
        for (int n = 0; n < 2; ++n)
          acc[m][n] = __builtin_amdgcn_mfma_f32_16x16x32_bf16(af[m], bfr[n], acc[m][n], 0, 0, 0);
    }
    if (i + 1 < 16) {
      if (i == 0) {
        VMWAIT(2)
      } else if (i + 2 < 16) {
        VMWAIT(4)
      } else {
        VMWAIT(0)
      }
      __builtin_amdgcn_s_barrier();
      __builtin_amdgcn_sched_barrier(0);
      if (i + 3 < 16) stageAW(i + 3);
    }
  }

  const int rg = lane >> 4;
  const bool even = (r15 & 1) == 0;
#pragma unroll
  for (int m = 0; m < 2; ++m) {
#pragma unroll
    for (int n = 0; n < 2; ++n) {
      const int col = n0 + wc * 32 + n * 16 + r15;  // interleaved mean/raw
      const int j = col >> 1;
      const float bv = bias[col];
#pragma unroll
      for (int i2 = 0; i2 < 4; ++i2) {
        const int row = m0 + wr * 32 + m * 16 + rg * 4 + i2;
        float v = acc[m][n][i2] + bv;
        float partner = __shfl_xor(v, 1);
        float mean = even ? v : partner;
        float raw = even ? partner : v;
        float sd = fminf(softplusf_(raw) + 0.1f, 5.0f);
        const size_t o = (size_t)row * SD + j;
        if (even) {
          float st = mean + sd * noise[o];
          ntstore4(mn_o + o, mean);
          ntstore4(st_o + o, st);
          if (isq) astore2(sprev + o, (unsigned)bfb(st * ntn[row]));
        } else {
          ntstore4(sd_o + o, sd);
        }
      }
    }
  }
}

struct Args {
  const float *prev_state, *actions, *prev_belief, *observations, *nonterminals,
      *me, *mp, *noise_p, *noise_q,
      *W_sa, *b_sa, *W_ih, *b_ih, *W_hh, *b_hh,
      *W_bp, *b_bp, *W_sp, *b_sp, *W_bq, *b_bq, *W_sq, *b_sq;
  float* out;
  unsigned* cnt;
  __hip_bfloat16 *Wsa, *Wih, *Whh, *Wbp, *Wbq, *Wsp, *Wsq;
  __hip_bfloat16 *actme, *obsmp, *sprev, *bel, *hid, *hpb, *hqb;
  float *gi, *gh, *hq_obs;
  float *bsp_ro, *bsq_ro;
};

// ---------------- prep ----------------
__global__ __launch_bounds__(256) void prep(Args P) {
  const int gtid = blockIdx.x * 256 + threadIdx.x;
  for (int i = gtid; i < BD * 576; i += PGSZ) {  // W_sa padded K 544->576
    int r = i / 576, k = i - r * 576;
    P.Wsa[i] = __float2bfloat16(k < 544 ? P.W_sa[(size_t)r * 544 + k] : 0.0f);
  }
  for (int i = gtid; i < 3 * BD * BD; i += PGSZ) P.Wih[i] = __float2bfloat16(P.W_ih[i]);
  for (int i = gtid; i < 3 * BD * BD; i += PGSZ) P.Whh[i] = __float2bfloat16(P.W_hh[i]);
  for (int i = gtid; i < HD * BD; i += PGSZ) P.Wbp[i] = __float2bfloat16(P.W_bp[i]);
  for (int i = gtid; i < HD * 2304; i += PGSZ) P.Wbq[i] = __float2bfloat16(P.W_bq[i]);
  for (int i = gtid; i < 512 * HD; i += PGSZ) {  // head W interleave
    int r = i >> 10, k = i & 1023;
    int dr = (r < 256) ? (2 * r) : (2 * (r - 256) + 1);
    P.Wsp[(size_t)dr * 1024 + k] = __float2bfloat16(P.W_sp[i]);
    P.Wsq[(size_t)dr * 1024 + k] = __float2bfloat16(P.W_sq[i]);
  }
  for (int i = gtid; i < 512; i += PGSZ) {
    int dr = (i < 256) ? (2 * i) : (2 * (i - 256) + 1);
    P.bsp_ro[dr] = P.b_sp[i];
    P.bsq_ro[dr] = P.b_sq[i];
  }
  for (int i = gtid; i < NT * NB * 320; i += PGSZ) {  // [act(32)|me(256)|pad(32)]
    int tb = i / 320, j = i - tb * 320;
    float v = (j < 32) ? P.actions[(size_t)tb * 32 + j]
                       : (j < 288 ? P.me[(size_t)tb * 256 + (j - 32)] : 0.0f);
    P.actme[i] = __float2bfloat16(v);
  }
  for (int i = gtid; i < NB * 1280; i += PGSZ) {  // obsmp(0)
    int bb = i / 1280, j = i - bb * 1280;
    float v = (j < ED) ? P.observations[(size_t)bb * ED + j] : P.mp[(size_t)bb * MD + (j - ED)];
    P.obsmp[i] = __float2bfloat16(v);
  }
  for (int i = gtid; i < NB * SD; i += PGSZ) {
    int r = i >> 8;
    P.sprev[i] = __float2bfloat16(P.prev_state[i] * P.nonterminals[r]);
  }
  for (int i = gtid; i < NB * BD; i += PGSZ) P.bel[i] = __float2bfloat16(P.prev_belief[i]);
}

// ---------------- mega: XCD m-partition, slot-map, cross-phase W-prefetch ----------------
__global__ __launch_bounds__(256, 2) void mega(Args P) {
  __shared__ alignas(16) char lds[73728];  // 48K ring + 24K wpre
  __shared__ int sh[4];
  const int tid = threadIdx.x;

  if (tid == 0) {
    unsigned x;
    asm volatile("s_getreg_b32 %0, hwreg(HW_REG_XCC_ID)" : "=s"(x));
    x &= 7u;
    unsigned s = __hip_atomic_fetch_add(P.cnt + x * 16, 1u, __ATOMIC_RELAXED,
                                        __HIP_MEMORY_SCOPE_AGENT);
    sh[0] = (int)x;
    sh[1] = (int)s;
  }
  __syncthreads();
  const int xcd = sh[0], slot = sh[1];

  if (tid == 0) {
    __hip_atomic_fetch_add(P.cnt + 128, 1u, __ATOMIC_RELAXED, __HIP_MEMORY_SCOPE_AGENT);
    while (__hip_atomic_load(P.cnt + 128, __ATOMIC_RELAXED, __HIP_MEMORY_SCOPE_AGENT) <
           (unsigned)NBLK)
      __builtin_amdgcn_s_sleep(4);
    sh[2] = (int)__hip_atomic_load(P.cnt + xcd * 16, __ATOMIC_RELAXED,
                                   __HIP_MEMORY_SCOPE_AGENT);
  }
  __syncthreads();
  const int nx = sh[2];
  const int m0 = xcd * 64;
  const size_t o_ps = (size_t)NT * NB * BD;
  const size_t blk = (size_t)NT * NB * SD;

  // next-job W for each phase's FIRST job of this slot (static slot map)
  const __hip_bfloat16* wA = nullptr; int lA = 0;   // phase A first job
  if (slot < 16) { wA = P.Wsa + (size_t)slot * 64 * 576; lA = 576; }
  else if (slot < 64) { wA = P.Whh + (size_t)(slot - 16) * 64 * BD; lA = BD; }
  const __hip_bfloat16* wB = nullptr; int lB = 0;
  if (slot < 48) { wB = P.Wih + (size_t)slot * 64 * BD; lB = BD; }
  else if (slot < 64) { wB = P.Wbq + (size_t)(slot - 48) * 64 * 2304 + 1024; lB = 2304; }
  const __hip_bfloat16* wD = nullptr; int lD = 0;
  if (slot < 16) { wD = P.Wbp + (size_t)slot * 64 * BD; lD = BD; }
  else if (slot < 32) { wD = P.Wbq + (size_t)(slot - 16) * 64 * 2304; lD = 2304; }
  const __hip_bfloat16* wE = nullptr; int lE = 0;
  if (slot < 8) { wE = P.Wsp + (size_t)slot * 64 * BD; lE = BD; }
  else if (slot < 16) { wE = P.Wsq + (size_t)(slot - 8) * 64 * BD; lE = BD; }

  if (wA) wpre_issue(wA, lA, lds, tid);  // t=0 phase-A prefetch (no wait)

  for (int t = 0; t < NT; ++t) {
    const int inst = t * 5;
    // ---- A: hid (16 jobs, 9 it) || gh (48 jobs, 16 it) ----
    for (int tt = slot; tt < 64; tt += nx) {
      const bool pre = (tt == slot);
      if (tt < 16) {
        gemm64(1, lds, pre, P.sprev, SD, P.actme + (size_t)t * NB * 320, 320, 256,
               P.Wsa + (size_t)tt * 64 * 576, 576, 9,
               P.b_sa + tt * 64, nullptr, nullptr, P.hid + tt * 64, BD, m0);
      } else {
        const int n = tt - 16;
        gemm64(0, lds, pre, P.bel, BD, nullptr, 0, K1BIG,
               P.Whh + (size_t)n * 64 * BD, BD, 16,
               P.b_hh + n * 64, nullptr, P.gh + n * 64, nullptr, 3 * BD, m0);
      }
    }
    xbar_pf(P.cnt, inst + 0, xcd, nx, wB, lB, lds, tid);
    // ---- B: gi (48 jobs, 16 it) || hq_obs (16 jobs, 20 it) ----
    for (int tt = slot; tt < 64; tt += nx) {
      const bool pre = (tt == slot);
      if (tt < 48) {
        gemm64(0, lds, pre, P.hid, BD, nullptr, 0, K1BIG,
               P.Wih + (size_t)tt * 64 * BD, BD, 16,
               P.b_ih + tt * 64, nullptr, P.gi + tt * 64, nullptr, 3 * BD, m0);
      } else {
        const int n = tt - 48;
        gemm64(0, lds, pre, P.obsmp, 1280, nullptr, 0, K1BIG,
               P.Wbq + (size_t)n * 64 * 2304 + 1024, 2304, 20,
               nullptr, nullptr, P.hq_obs + n * 64, nullptr, 1024, m0);
      }
    }
    xbar_pf(P.cnt, inst + 1, xcd, nx, wD, lD, lds, tid);  // prefetch D (survives C)
    // ---- C: GRU pointwise (rows m0..m0+63) + obsmp(t+1) pack ----
    for (int u = slot * 256 + tid; u < 8192; u += nx * 256) {
      const int r = m0 + (u >> 7), j0 = (u & 127) << 3;
      const float* gib = P.gi + (size_t)r * 3072 + j0;
      const float* ghb = P.gh + (size_t)r * 3072 + j0;
      f32x4 ir0, ir1, iz0, iz1, in0, in1, hr0, hr1, hz0, hz1, hn0, hn1, hbv;
      aload16(gib, &ir0);
      aload16(gib + 4, &ir1);
      aload16(gib + 1024, &iz0);
      aload16(gib + 1028, &iz1);
      aload16(gib + 2048, &in0);
      aload16(gib + 2052, &in1);
      aload16(ghb, &hr0);
      aload16(ghb + 4, &hr1);
      aload16(ghb + 1024, &hz0);
      aload16(ghb + 1028, &hz1);
      aload16(ghb + 2048, &hn0);
      aload16(ghb + 2052, &hn1);
      aload16(P.bel + (size_t)r * BD + j0, &hbv);
      VMWAIT(0)
      bf16x8 hb = __builtin_bit_cast(bf16x8, hbv);
      float o[8];
      unsigned short nb[8];
#pragma unroll
      for (int k = 0; k < 8; ++k) {
        float gr = (k < 4 ? ir0[k] : ir1[k - 4]) + (k < 4 ? hr0[k] : hr1[k - 4]);
        float gz = (k < 4 ? iz0[k] : iz1[k - 4]) + (k < 4 ? hz0[k] : hz1[k - 4]);
        float hn = (k < 4 ? hn0[k] : hn1[k - 4]);
        float in_ = (k < 4 ? in0[k] : in1[k - 4]);
        float r_ = sigmoidf_(gr);
        float z_ = sigmoidf_(gz);
        float n_ = tanhf(in_ + r_ * hn);
        __hip_bfloat16 hv16 = __builtin_bit_cast(__hip_bfloat16, (unsigned short)hb[k]);
        float hv = __bfloat162float(hv16);
        float bel = (1.0f - z_) * n_ + z_ * hv;
        o[k] = bel;
        nb[k] = bfb(bel);
      }
      float* ob = P.out + (size_t)t * NB * BD + (size_t)r * BD + j0;
      ntstore16(ob, f32x4{o[0], o[1], o[2], o[3]});
      ntstore16(ob + 4, f32x4{o[4], o[5], o[6], o[7]});
      astore16(P.bel + (size_t)r * BD + j0, __builtin_bit_cast(f32x4, *(bf16x8*)nb));
    }
    if (t + 1 < NT) {
      for (int v = slot * 256 + tid; v < 5120; v += nx * 256) {
        const int r = m0 + v / 80, c0 = (v % 80) << 4;
        const float* src = (c0 < ED)
            ? (P.observations + (size_t)(t + 1) * NB * ED + (size_t)r * ED + c0)
            : (P.mp + (size_t)(t + 1) * NB * MD + (size_t)r * MD + (c0 - ED));
        unsigned short nb[16];
#pragma unroll
        for (int q = 0; q < 4; ++q) {
          f32x4 vv = *(const f32x4*)(src + q * 4);
#pragma unroll
          for (int kk = 0; kk < 4; ++kk) nb[q * 4 + kk] = bfb(vv[kk]);
        }
        astore16(P.obsmp + (size_t)r * 1280 + c0, __builtin_bit_cast(f32x4, *(bf16x8*)nb));
        astore16(P.obsmp + (size_t)r * 1280 + c0 + 8,
                 __builtin_bit_cast(f32x4, *(bf16x8*)(nb + 8)));
      }
    }
    xbar_pf(P.cnt, inst + 2, xcd, nx, nullptr, 0, lds, tid);  // D W already in wpre
    // ---- D: hp (16 jobs) || hq = bel@Wbq[:1024] + hq_obs (16 jobs) ----
    for (int tt = slot; tt < 32; tt += nx) {
      const bool pre = (tt == slot);
      if (tt < 16) {
        gemm64(1, lds, pre, P.bel, BD, nullptr, 0, K1BIG,
               P.Wbp + (size_t)tt * 64 * BD, BD, 16,
               P.b_bp + tt * 64, nullptr, nullptr, P.hpb + tt * 64, HD, m0);
      } else {
        const int n = tt - 16;
        gemm64(3, lds, pre, P.bel, BD, nullptr, 0, K1BIG,
               P.Wbq + (size_t)n * 64 * 2304, 2304, 16,
               P.b_bq + n * 64, P.hq_obs + n * 64, nullptr, P.hqb + n * 64, HD, m0);
      }
    }
    xbar_pf(P.cnt, inst + 3, xcd, nx, wE, lE, lds, tid);
    // ---- E: p/q heads with fused epilogue + sprev carry (16 jobs) ----
    {
      const float* ntn = P.nonterminals + (size_t)((t + 1 < NT) ? t + 1 : t) * NB;
      const size_t to = (size_t)t * NB * SD;
      for (int tt = slot; tt < 16; tt += nx) {
        const bool pre = (tt == slot);
        if (tt < 8)
          gemm_head64(lds, pre, P.hpb, P.Wsp + (size_t)tt * 64 * BD, P.bsp_ro,
                      P.noise_p + to, P.out + o_ps + to, P.out + o_ps + blk + to,
                      P.out + o_ps + 2 * blk + to, ntn, P.sprev, 0, tt * 64, m0);
        else
          gemm_head64(lds, pre, P.hqb, P.Wsq + (size_t)(tt - 8) * 64 * BD, P.bsq_ro,
                      P.noise_q + to, P.out + o_ps + 3 * blk + to,
                      P.out + o_ps + 4 * blk + to, P.out + o_ps + 5 * blk + to,
                      ntn, P.sprev, 1, (tt - 8) * 64, m0);
      }
    }
    xbar_pf(P.cnt, inst + 4, xcd, nx, wA, lA, lds, tid);  // prefetch next-t phase A
  }
}

// ---------------- host ----------------

extern "C" void kernel_launch(void* const* d_in, const int* in_sizes, int n_in,
                              void* d_out, int out_size, void* d_ws, size_t ws_size,
                              hipStream_t stream) {
  Args P;
  P.prev_state = (const float*)d_in[0];
  P.actions = (const float*)d_in[1];
  P.prev_belief = (const float*)d_in[2];
  P.observations = (const float*)d_in[3];
  P.nonterminals = (const float*)d_in[4];
  P.me = (const float*)d_in[5];
  P.mp = (const float*)d_in[6];
  P.noise_p = (const float*)d_in[7];
  P.noise_q = (const float*)d_in[8];
  P.W_sa = (const float*)d_in[9];  P.b_sa = (const float*)d_in[10];
  P.W_ih = (const float*)d_in[11]; P.b_ih = (const float*)d_in[12];
  P.W_hh = (const float*)d_in[13]; P.b_hh = (const float*)d_in[14];
  P.W_bp = (const float*)d_in[15]; P.b_bp = (const float*)d_in[16];
  P.W_sp = (const float*)d_in[17]; P.b_sp = (const float*)d_in[18];
  P.W_bq = (const float*)d_in[19]; P.b_bq = (const float*)d_in[20];
  P.W_sq = (const float*)d_in[21]; P.b_sq = (const float*)d_in[22];
  P.out = (float*)d_out;

  char* p = (char*)d_ws;
  auto carve = [&](size_t bytes) -> char* {
    char* r = p;
    p += (bytes + 255) & ~(size_t)255;
    return r;
  };
  const size_t cnt_bytes = (size_t)65536 * 4;
  P.cnt = (unsigned*)carve(cnt_bytes);
  P.Wsa = (__hip_bfloat16*)carve((size_t)BD * 576 * 2);
  P.Wih = (__hip_bfloat16*)carve((size_t)3 * BD * BD * 2);
  P.Whh = (__hip_bfloat16*)carve((size_t)3 * BD * BD * 2);
  P.Wbp = (__hip_bfloat16*)carve((size_t)HD * BD * 2);
  P.Wbq = (__hip_bfloat16*)carve((size_t)HD * 2304 * 2);
  P.Wsp = (__hip_bfloat16*)carve((size_t)512 * HD * 2);
  P.Wsq = (__hip_bfloat16*)carve((size_t)512 * HD * 2);
  P.bsp_ro = (float*)carve(512 * 4);
  P.bsq_ro = (float*)carve(512 * 4);
  P.actme = (__hip_bfloat16*)carve((size_t)NT * NB * 320 * 2);
  P.obsmp = (__hip_bfloat16*)carve((size_t)NB * 1280 * 2);
  P.sprev = (__hip_bfloat16*)carve((size_t)NB * SD * 2);
  P.bel = (__hip_bfloat16*)carve((size_t)NB * BD * 2);
  P.hid = (__hip_bfloat16*)carve((size_t)NB * BD * 2);
  P.hpb = (__hip_bfloat16*)carve((size_t)NB * HD * 2);
  P.hqb = (__hip_bfloat16*)carve((size_t)NB * HD * 2);
  P.gi = (float*)carve((size_t)NB * 3 * BD * 4);
  P.gh = (float*)carve((size_t)NB * 3 * BD * 4);
  P.hq_obs = (float*)carve((size_t)NB * HD * 4);

  hipMemsetAsync(P.cnt, 0, cnt_bytes, stream);
  prep<<<1024, 256, 0, stream>>>(P);
  mega<<<NBLK, 256, 0, stream>>>(P);
}